// Round 10
// baseline (98.372 us; speedup 1.0000x reference)
//
#include <hip/hip_runtime.h>
#include <math.h>

// FFF sparse tree forward. B=16384, D_IN=D_OUT=768, DEPTH=11, n_nodes=4095.
//
// One wave per sample; lane owns 12 dims (3x float4 at lane + j*64).
// Phase-split (R5/R9 structure) + DEPTH-1 SPECULATIVE PREFETCH:
//   Phase 1: per level, while computing the current f32 dot + DPP reduce,
//     BOTH children W1 rows are already in flight (addresses depend only on
//     the current node, so they issue a full level early). After the sign,
//     a register cndmask selects the winner. The level-to-level critical
//     path is now pure load latency; compute is fully overlapped.
//     Rare f64 fallback when |p| < 1e-4 keeps routing == f64 reference.
//   Phase 2: replay node sequence from bit mask; 12 independent w2 row
//     gathers + f32 fma; coalesced float4 store. Unchanged from R9.
//
// R9 post-mortem: R5 (75us), R6 (74us, 2x chains/wave), R9 (73us, reduce
// chain -200cy/lvl) all identical -> chain compute is not the wall. This
// round discriminates gather-latency vs byte-throughput: speculation
// shortens the serial chain but doubles phase-1 W1 bytes. Faster => latency;
// slower => throughput (then attack bytes next).
// Tripwires: VGPR <= 96, WRITE_SIZE == 49152 KB (spill detector).

#define FFF_LVLS 12        // depth+1
#define FFF_D 768
#define FFF_ROWF4 192      // float4 per 768-f32 row

__device__ __forceinline__ float gelu_exact(float v) {
    return 0.5f * v * (1.0f + erff(v * 0.70710678118654752440f));
}

// v += (v from N lanes lower within each 16-lane row); OOB lanes add 0
// (bound_ctrl=true). Builtin form: compiler inserts DPP hazard wait-states.
template <int CTRL>
__device__ __forceinline__ float dpp_shr_add(float v) {
    const int t = __builtin_amdgcn_update_dpp(
        0, __builtin_bit_cast(int, v), CTRL, 0xf, 0xf, true);
    return v + __builtin_bit_cast(float, t);
}

// Wave64 sum, pure VALU. After 4 row_shr steps lanes 15/31/47/63 hold each
// 16-lane row's total; 4 readlanes + 3 adds -> wave-uniform sum.
__device__ __forceinline__ float wave_allsum_f32(float v) {
    v = dpp_shr_add<0x111>(v);   // row_shr:1
    v = dpp_shr_add<0x112>(v);   // row_shr:2
    v = dpp_shr_add<0x114>(v);   // row_shr:4
    v = dpp_shr_add<0x118>(v);   // row_shr:8
    const int i15 = __builtin_amdgcn_readlane(__builtin_bit_cast(int, v), 15);
    const int i31 = __builtin_amdgcn_readlane(__builtin_bit_cast(int, v), 31);
    const int i47 = __builtin_amdgcn_readlane(__builtin_bit_cast(int, v), 47);
    const int i63 = __builtin_amdgcn_readlane(__builtin_bit_cast(int, v), 63);
    return (__builtin_bit_cast(float, i15) + __builtin_bit_cast(float, i31))
         + (__builtin_bit_cast(float, i47) + __builtin_bit_cast(float, i63));
}

__global__ void __launch_bounds__(256) fff_sparse_kernel(
    const float* __restrict__ x,
    const float* __restrict__ w1s,
    const float* __restrict__ w2s,
    float* __restrict__ out,
    int B)
{
    const int wave = threadIdx.x >> 6;
    const int lane = threadIdx.x & 63;
    const int b = blockIdx.x * 4 + wave;
    if (b >= B) return;

    const float4* __restrict__ xf4  = (const float4*)x;
    const float4* __restrict__ w1f4 = (const float4*)w1s;
    const float4* __restrict__ w2f4 = (const float4*)w2s;

    // x row in registers, coalesced.
    const int xb = b * FFF_ROWF4 + lane;
    const float4 xv0 = xf4[xb];
    const float4 xv1 = xf4[xb + 64];
    const float4 xv2 = xf4[xb + 128];

    // ---- Phase 1: tree walk with both-children speculation.
    float acts[FFF_LVLS];
    int bits = 0;
    int node = 0;

    // Root row.
    float4 c0 = w1f4[lane];
    float4 c1 = w1f4[lane + 64];
    float4 c2 = w1f4[lane + 128];

#pragma unroll
    for (int lvl = 0; lvl < FFF_LVLS; ++lvl) {
        // Speculative loads of BOTH children rows — issue before the dot so
        // their latency overlaps this level's compute (and then some).
        float4 l0, l1, l2, r0, r1, r2;
        if (lvl + 1 < FFF_LVLS) {
            const int cl = (2 * node + 1) * FFF_ROWF4 + lane;
            l0 = w1f4[cl];
            l1 = w1f4[cl + 64];
            l2 = w1f4[cl + 128];
            r0 = w1f4[cl + FFF_ROWF4];
            r1 = w1f4[cl + FFF_ROWF4 + 64];
            r2 = w1f4[cl + FFF_ROWF4 + 128];
        }

        // f32 dot, two chains.
        float q0 = xv0.x * c0.x;
        float q1 = xv0.y * c0.y;
        q0 = fmaf(xv0.z, c0.z, q0);
        q1 = fmaf(xv0.w, c0.w, q1);
        q0 = fmaf(xv1.x, c1.x, q0);
        q1 = fmaf(xv1.y, c1.y, q1);
        q0 = fmaf(xv1.z, c1.z, q0);
        q1 = fmaf(xv1.w, c1.w, q1);
        q0 = fmaf(xv2.x, c2.x, q0);
        q1 = fmaf(xv2.y, c2.y, q1);
        q0 = fmaf(xv2.z, c2.z, q0);
        q1 = fmaf(xv2.w, c2.w, q1);

        float p = wave_allsum_f32(q0 + q1);   // wave-uniform

        // Rare wave-uniform f64 fallback (sign ambiguous at f32: ~2e-4).
        if (__builtin_expect(fabsf(p) < 1e-4f, 0)) {
            double d0 = (double)xv0.x * (double)c0.x;
            double d1 = (double)xv0.y * (double)c0.y;
            d0 += (double)xv0.z * (double)c0.z;
            d1 += (double)xv0.w * (double)c0.w;
            d0 += (double)xv1.x * (double)c1.x;
            d1 += (double)xv1.y * (double)c1.y;
            d0 += (double)xv1.z * (double)c1.z;
            d1 += (double)xv1.w * (double)c1.w;
            d0 += (double)xv2.x * (double)c2.x;
            d1 += (double)xv2.y * (double)c2.y;
            d0 += (double)xv2.z * (double)c2.z;
            d1 += (double)xv2.w * (double)c2.w;
            double pd = d0 + d1;
#pragma unroll
            for (int m = 32; m > 0; m >>= 1) pd += __shfl_xor(pd, m, 64);
            p = (float)pd;
        }

        acts[lvl] = gelu_exact(p);
        const int s = (p >= 0.0f) ? 1 : 0;
        bits |= s << lvl;
        node = 2 * node + 1 + s;

        if (lvl + 1 < FFF_LVLS) {
            // Select the winning child row (register cndmask; loads already
            // in flight since before the dot).
            c0 = s ? r0 : l0;
            c1 = s ? r1 : l1;
            c2 = s ? r2 : l2;
        }
    }

    // ---- Phase 2: w2 accumulation (12 gathers, 3-op ALU chain only).
    float4 acc0 = make_float4(0.f, 0.f, 0.f, 0.f);
    float4 acc1 = make_float4(0.f, 0.f, 0.f, 0.f);
    float4 acc2 = make_float4(0.f, 0.f, 0.f, 0.f);

    node = 0;
#pragma unroll
    for (int lvl = 0; lvl < FFF_LVLS; ++lvl) {
        const int r = node * FFF_ROWF4 + lane;
        const float4 w0 = w2f4[r];
        const float4 w1 = w2f4[r + 64];
        const float4 w2 = w2f4[r + 128];
        const float a = acts[lvl];
        acc0.x = fmaf(a, w0.x, acc0.x); acc0.y = fmaf(a, w0.y, acc0.y);
        acc0.z = fmaf(a, w0.z, acc0.z); acc0.w = fmaf(a, w0.w, acc0.w);
        acc1.x = fmaf(a, w1.x, acc1.x); acc1.y = fmaf(a, w1.y, acc1.y);
        acc1.z = fmaf(a, w1.z, acc1.z); acc1.w = fmaf(a, w1.w, acc1.w);
        acc2.x = fmaf(a, w2.x, acc2.x); acc2.y = fmaf(a, w2.y, acc2.y);
        acc2.z = fmaf(a, w2.z, acc2.z); acc2.w = fmaf(a, w2.w, acc2.w);
        node = 2 * node + 1 + ((bits >> lvl) & 1);
    }

    float4* __restrict__ of4 = (float4*)out;
    const int ob = b * FFF_ROWF4 + lane;
    of4[ob]       = acc0;
    of4[ob + 64]  = acc1;
    of4[ob + 128] = acc2;
}

extern "C" void kernel_launch(void* const* d_in, const int* in_sizes, int n_in,
                              void* d_out, int out_size, void* d_ws, size_t ws_size,
                              hipStream_t stream) {
    const float* x   = (const float*)d_in[0];
    const float* w1s = (const float*)d_in[1];
    const float* w2s = (const float*)d_in[2];
    float* out = (float*)d_out;

    const int B = out_size / FFF_D;            // 16384
    const int blocks = (B + 3) / 4;            // 4 waves (samples) per block

    fff_sparse_kernel<<<blocks, 256, 0, stream>>>(x, w1s, w2s, out, B);
}

// Round 11
// 70.578 us; speedup vs baseline: 1.3938x; 1.3938x over previous
//
#include <hip/hip_runtime.h>
#include <math.h>

// FFF sparse tree forward. B=16384, D_IN=D_OUT=768, DEPTH=11, n_nodes=4095.
//
// One wave per sample; lane owns 12 dims (3x float4 at lane + j*64).
// Phase-split (R5/R9 structure, 52 VGPR, no spill):
//   Phase 1: tree walk. gather W1[node] row -> f32 dot -> DPP wave64 reduce
//     -> sign + exact-erf GELU; |p|<1e-4 -> rare f64 recompute (sign matches
//     f64 numpy reference).
//   Phase 2: replay nodes from bit mask; 12 independent w2 gathers + fma.
//
// R10 post-mortem: both-children speculation = +48% bytes -> +34% time.
// Byte-throughput-bound, so speculation reverted. R11 changes ONE variable:
// block size 256 -> 1024 (16 waves/block). Occupancy counter has been stuck
// at 12-15 waves/CU (38-46%) despite 52 VGPR allowing 32; 16-wave blocks
// let 2 resident blocks hit the 32-wave cap -> more outstanding gathers ->
// TA/L2 pipeline fed across deep-level L3 round-trips.

#define FFF_LVLS 12        // depth+1
#define FFF_D 768
#define FFF_ROWF4 192      // float4 per 768-f32 row
#define WAVES_PER_BLOCK 16

__device__ __forceinline__ float gelu_exact(float v) {
    return 0.5f * v * (1.0f + erff(v * 0.70710678118654752440f));
}

// v += (v from N lanes lower within each 16-lane row); OOB lanes add 0
// (bound_ctrl=true). Builtin form: compiler inserts DPP hazard wait-states.
template <int CTRL>
__device__ __forceinline__ float dpp_shr_add(float v) {
    const int t = __builtin_amdgcn_update_dpp(
        0, __builtin_bit_cast(int, v), CTRL, 0xf, 0xf, true);
    return v + __builtin_bit_cast(float, t);
}

// Wave64 sum, pure VALU. After 4 row_shr steps lanes 15/31/47/63 hold each
// 16-lane row's total; 4 readlanes + 3 adds -> wave-uniform sum.
__device__ __forceinline__ float wave_allsum_f32(float v) {
    v = dpp_shr_add<0x111>(v);   // row_shr:1
    v = dpp_shr_add<0x112>(v);   // row_shr:2
    v = dpp_shr_add<0x114>(v);   // row_shr:4
    v = dpp_shr_add<0x118>(v);   // row_shr:8
    const int i15 = __builtin_amdgcn_readlane(__builtin_bit_cast(int, v), 15);
    const int i31 = __builtin_amdgcn_readlane(__builtin_bit_cast(int, v), 31);
    const int i47 = __builtin_amdgcn_readlane(__builtin_bit_cast(int, v), 47);
    const int i63 = __builtin_amdgcn_readlane(__builtin_bit_cast(int, v), 63);
    return (__builtin_bit_cast(float, i15) + __builtin_bit_cast(float, i31))
         + (__builtin_bit_cast(float, i47) + __builtin_bit_cast(float, i63));
}

__global__ void __launch_bounds__(1024) fff_sparse_kernel(
    const float* __restrict__ x,
    const float* __restrict__ w1s,
    const float* __restrict__ w2s,
    float* __restrict__ out,
    int B)
{
    const int wave = threadIdx.x >> 6;
    const int lane = threadIdx.x & 63;
    const int b = blockIdx.x * WAVES_PER_BLOCK + wave;
    if (b >= B) return;

    const float4* __restrict__ xf4  = (const float4*)x;
    const float4* __restrict__ w1f4 = (const float4*)w1s;
    const float4* __restrict__ w2f4 = (const float4*)w2s;

    // x row in registers, coalesced.
    const int xb = b * FFF_ROWF4 + lane;
    const float4 xv0 = xf4[xb];
    const float4 xv1 = xf4[xb + 64];
    const float4 xv2 = xf4[xb + 128];

    // ---- Phase 1: tree walk (W1 only; acts + routing bits recorded).
    float acts[FFF_LVLS];
    int bits = 0;
    int node = 0;

#pragma unroll
    for (int lvl = 0; lvl < FFF_LVLS; ++lvl) {
        const int r = node * FFF_ROWF4 + lane;
        const float4 a0 = w1f4[r];
        const float4 a1 = w1f4[r + 64];
        const float4 a2 = w1f4[r + 128];

        // f32 dot, two chains.
        float q0 = xv0.x * a0.x;
        float q1 = xv0.y * a0.y;
        q0 = fmaf(xv0.z, a0.z, q0);
        q1 = fmaf(xv0.w, a0.w, q1);
        q0 = fmaf(xv1.x, a1.x, q0);
        q1 = fmaf(xv1.y, a1.y, q1);
        q0 = fmaf(xv1.z, a1.z, q0);
        q1 = fmaf(xv1.w, a1.w, q1);
        q0 = fmaf(xv2.x, a2.x, q0);
        q1 = fmaf(xv2.y, a2.y, q1);
        q0 = fmaf(xv2.z, a2.z, q0);
        q1 = fmaf(xv2.w, a2.w, q1);

        float p = wave_allsum_f32(q0 + q1);   // wave-uniform

        // Rare wave-uniform fallback: f32 sum error ~1e-6, so only
        // |p| < 1e-4 can have an f32/f64 sign discrepancy (~2e-4 of levels).
        if (__builtin_expect(fabsf(p) < 1e-4f, 0)) {
            double d0 = (double)xv0.x * (double)a0.x;
            double d1 = (double)xv0.y * (double)a0.y;
            d0 += (double)xv0.z * (double)a0.z;
            d1 += (double)xv0.w * (double)a0.w;
            d0 += (double)xv1.x * (double)a1.x;
            d1 += (double)xv1.y * (double)a1.y;
            d0 += (double)xv1.z * (double)a1.z;
            d1 += (double)xv1.w * (double)a1.w;
            d0 += (double)xv2.x * (double)a2.x;
            d1 += (double)xv2.y * (double)a2.y;
            d0 += (double)xv2.z * (double)a2.z;
            d1 += (double)xv2.w * (double)a2.w;
            double pd = d0 + d1;
#pragma unroll
            for (int m = 32; m > 0; m >>= 1) pd += __shfl_xor(pd, m, 64);
            p = (float)pd;
        }

        acts[lvl] = gelu_exact(p);
        const int s = (p >= 0.0f) ? 1 : 0;
        bits |= s << lvl;
        node = 2 * node + 1 + s;
    }

    // ---- Phase 2: w2 accumulation (12 gathers, 3-op ALU chain only).
    float4 acc0 = make_float4(0.f, 0.f, 0.f, 0.f);
    float4 acc1 = make_float4(0.f, 0.f, 0.f, 0.f);
    float4 acc2 = make_float4(0.f, 0.f, 0.f, 0.f);

    node = 0;
#pragma unroll
    for (int lvl = 0; lvl < FFF_LVLS; ++lvl) {
        const int r = node * FFF_ROWF4 + lane;
        const float4 c0 = w2f4[r];
        const float4 c1 = w2f4[r + 64];
        const float4 c2 = w2f4[r + 128];
        const float a = acts[lvl];
        acc0.x = fmaf(a, c0.x, acc0.x); acc0.y = fmaf(a, c0.y, acc0.y);
        acc0.z = fmaf(a, c0.z, acc0.z); acc0.w = fmaf(a, c0.w, acc0.w);
        acc1.x = fmaf(a, c1.x, acc1.x); acc1.y = fmaf(a, c1.y, acc1.y);
        acc1.z = fmaf(a, c1.z, acc1.z); acc1.w = fmaf(a, c1.w, acc1.w);
        acc2.x = fmaf(a, c2.x, acc2.x); acc2.y = fmaf(a, c2.y, acc2.y);
        acc2.z = fmaf(a, c2.z, acc2.z); acc2.w = fmaf(a, c2.w, acc2.w);
        node = 2 * node + 1 + ((bits >> lvl) & 1);
    }

    float4* __restrict__ of4 = (float4*)out;
    const int ob = b * FFF_ROWF4 + lane;
    of4[ob]       = acc0;
    of4[ob + 64]  = acc1;
    of4[ob + 128] = acc2;
}

extern "C" void kernel_launch(void* const* d_in, const int* in_sizes, int n_in,
                              void* d_out, int out_size, void* d_ws, size_t ws_size,
                              hipStream_t stream) {
    const float* x   = (const float*)d_in[0];
    const float* w1s = (const float*)d_in[1];
    const float* w2s = (const float*)d_in[2];
    float* out = (float*)d_out;

    const int B = out_size / FFF_D;                        // 16384
    const int blocks = (B + WAVES_PER_BLOCK - 1) / WAVES_PER_BLOCK;  // 1024

    fff_sparse_kernel<<<blocks, WAVES_PER_BLOCK * 64, 0, stream>>>(
        x, w1s, w2s, out, B);
}

// Round 12
// 64.097 us; speedup vs baseline: 1.5347x; 1.1011x over previous
//
#include <hip/hip_runtime.h>
#include <math.h>

// FFF sparse tree forward. B=16384, D_IN=D_OUT=768, DEPTH=11, n_nodes=4095.
//
// R10/R11 established the kernel is gathered-BYTE-throughput-bound
// (~1.28 GB logical traffic @ ~18 TB/s effective; speculation's +48% bytes
// cost +34% time; occupancy + chain-compute changes were neutral).
// R12 halves the gather bytes: W1/w2 staged as bf16 in d_ws by a conversion
// pre-kernel. Routing sign stays EXACT vs the f64 numpy reference: when
// |p_bf16| < 0.03 (~23 sigma of bf16-dot error, ~4% of levels) the level is
// recomputed from the original f32 w1s with the f64 dot + shfl butterfly
// (the R5-proven path). Act precision from bf16 weights (~1.5e-3) perturbs
// out by ~1e-4 << 1.65e-3 threshold (|w2| <= 0.0156, 12 terms).
//
// Tripwires: WRITE_SIZE ~= 61.5 MB (49152 out + 12285 bf16); VGPR <= 64.

#define FFF_LVLS 12        // depth+1
#define FFF_D 768
#define FFF_ROWF4 192      // float4 per 768-f32 row
#define FFF_NODES 4095
#define WAVES_PER_BLOCK 16

__device__ __forceinline__ float gelu_exact(float v) {
    return 0.5f * v * (1.0f + erff(v * 0.70710678118654752440f));
}

__device__ __forceinline__ unsigned short f32_to_bf16_rne(float f) {
    unsigned int u = __builtin_bit_cast(unsigned int, f);
    u += 0x7FFFu + ((u >> 16) & 1u);
    return (unsigned short)(u >> 16);
}
__device__ __forceinline__ float bf16_to_f32(unsigned short h) {
    return __builtin_bit_cast(float, (unsigned int)h << 16);
}

// v += (v from N lanes lower within each 16-lane row); OOB adds 0.
template <int CTRL>
__device__ __forceinline__ float dpp_shr_add(float v) {
    const int t = __builtin_amdgcn_update_dpp(
        0, __builtin_bit_cast(int, v), CTRL, 0xf, 0xf, true);
    return v + __builtin_bit_cast(float, t);
}

// Wave64 sum, pure VALU; lanes 15/31/47/63 hold row totals after 4 steps.
__device__ __forceinline__ float wave_allsum_f32(float v) {
    v = dpp_shr_add<0x111>(v);   // row_shr:1
    v = dpp_shr_add<0x112>(v);   // row_shr:2
    v = dpp_shr_add<0x114>(v);   // row_shr:4
    v = dpp_shr_add<0x118>(v);   // row_shr:8
    const int i15 = __builtin_amdgcn_readlane(__builtin_bit_cast(int, v), 15);
    const int i31 = __builtin_amdgcn_readlane(__builtin_bit_cast(int, v), 31);
    const int i47 = __builtin_amdgcn_readlane(__builtin_bit_cast(int, v), 47);
    const int i63 = __builtin_amdgcn_readlane(__builtin_bit_cast(int, v), 63);
    return (__builtin_bit_cast(float, i15) + __builtin_bit_cast(float, i31))
         + (__builtin_bit_cast(float, i47) + __builtin_bit_cast(float, i63));
}

// f32 -> bf16 staging of W1 and w2 (runs each call; deterministic).
__global__ void __launch_bounds__(1024) fff_convert_kernel(
    const float4* __restrict__ w1, const float4* __restrict__ w2,
    ushort4* __restrict__ o1, ushort4* __restrict__ o2, int nf4)
{
    int i = blockIdx.x * blockDim.x + threadIdx.x;
    if (i < nf4) {
        const float4 v = w1[i];
        ushort4 h;
        h.x = f32_to_bf16_rne(v.x); h.y = f32_to_bf16_rne(v.y);
        h.z = f32_to_bf16_rne(v.z); h.w = f32_to_bf16_rne(v.w);
        o1[i] = h;
    } else if (i < 2 * nf4) {
        const int j = i - nf4;
        const float4 v = w2[j];
        ushort4 h;
        h.x = f32_to_bf16_rne(v.x); h.y = f32_to_bf16_rne(v.y);
        h.z = f32_to_bf16_rne(v.z); h.w = f32_to_bf16_rne(v.w);
        o2[j] = h;
    }
}

__global__ void __launch_bounds__(1024) fff_sparse_kernel_bf16(
    const float* __restrict__ x,
    const float* __restrict__ w1s,          // f32, fallback only
    const ushort4* __restrict__ w1b,        // bf16 rows, 192 ushort4/row
    const ushort4* __restrict__ w2b,
    float* __restrict__ out,
    int B)
{
    const int wave = threadIdx.x >> 6;
    const int lane = threadIdx.x & 63;
    const int b = blockIdx.x * WAVES_PER_BLOCK + wave;
    if (b >= B) return;

    const float4* __restrict__ xf4  = (const float4*)x;
    const float4* __restrict__ w1f4 = (const float4*)w1s;

    // x row in registers, coalesced. Dim mapping: lane*4 + j*256 + {0..3} —
    // identical to the bf16 ushort4 layout below.
    const int xb = b * FFF_ROWF4 + lane;
    const float4 xv0 = xf4[xb];
    const float4 xv1 = xf4[xb + 64];
    const float4 xv2 = xf4[xb + 128];

    // ---- Phase 1: tree walk on bf16 W1; exact-sign fallback on f32/f64.
    float acts[FFF_LVLS];
    int bits = 0;
    int node = 0;

#pragma unroll
    for (int lvl = 0; lvl < FFF_LVLS; ++lvl) {
        const ushort4* __restrict__ rw = w1b + node * FFF_ROWF4;
        const ushort4 h0 = rw[lane];
        const ushort4 h1 = rw[lane + 64];
        const ushort4 h2 = rw[lane + 128];

        // f32 dot on bf16-rounded weights, two chains.
        float q0 = xv0.x * bf16_to_f32(h0.x);
        float q1 = xv0.y * bf16_to_f32(h0.y);
        q0 = fmaf(xv0.z, bf16_to_f32(h0.z), q0);
        q1 = fmaf(xv0.w, bf16_to_f32(h0.w), q1);
        q0 = fmaf(xv1.x, bf16_to_f32(h1.x), q0);
        q1 = fmaf(xv1.y, bf16_to_f32(h1.y), q1);
        q0 = fmaf(xv1.z, bf16_to_f32(h1.z), q0);
        q1 = fmaf(xv1.w, bf16_to_f32(h1.w), q1);
        q0 = fmaf(xv2.x, bf16_to_f32(h2.x), q0);
        q1 = fmaf(xv2.y, bf16_to_f32(h2.y), q1);
        q0 = fmaf(xv2.z, bf16_to_f32(h2.z), q0);
        q1 = fmaf(xv2.w, bf16_to_f32(h2.w), q1);

        float p = wave_allsum_f32(q0 + q1);   // wave-uniform

        // Sign-ambiguity fallback: bf16-dot error sigma ~1.3e-3; |p| < 0.03
        // (~23 sigma, ~4% of levels) -> recompute from ORIGINAL f32 weights
        // in f64 (R5-proven path) so routing matches the f64 reference.
        if (__builtin_expect(fabsf(p) < 0.03f, 0)) {
            const int r = node * FFF_ROWF4 + lane;
            const float4 a0 = w1f4[r];
            const float4 a1 = w1f4[r + 64];
            const float4 a2 = w1f4[r + 128];
            double d0 = (double)xv0.x * (double)a0.x;
            double d1 = (double)xv0.y * (double)a0.y;
            d0 += (double)xv0.z * (double)a0.z;
            d1 += (double)xv0.w * (double)a0.w;
            d0 += (double)xv1.x * (double)a1.x;
            d1 += (double)xv1.y * (double)a1.y;
            d0 += (double)xv1.z * (double)a1.z;
            d1 += (double)xv1.w * (double)a1.w;
            d0 += (double)xv2.x * (double)a2.x;
            d1 += (double)xv2.y * (double)a2.y;
            d0 += (double)xv2.z * (double)a2.z;
            d1 += (double)xv2.w * (double)a2.w;
            double pd = d0 + d1;
#pragma unroll
            for (int m = 32; m > 0; m >>= 1) pd += __shfl_xor(pd, m, 64);
            p = (float)pd;
        }

        acts[lvl] = gelu_exact(p);
        const int s = (p >= 0.0f) ? 1 : 0;
        bits |= s << lvl;
        node = 2 * node + 1 + s;
    }

    // ---- Phase 2: bf16 w2 accumulation (12 gathers, 3-op ALU chain).
    float4 acc0 = make_float4(0.f, 0.f, 0.f, 0.f);
    float4 acc1 = make_float4(0.f, 0.f, 0.f, 0.f);
    float4 acc2 = make_float4(0.f, 0.f, 0.f, 0.f);

    node = 0;
#pragma unroll
    for (int lvl = 0; lvl < FFF_LVLS; ++lvl) {
        const ushort4* __restrict__ rw = w2b + node * FFF_ROWF4;
        const ushort4 h0 = rw[lane];
        const ushort4 h1 = rw[lane + 64];
        const ushort4 h2 = rw[lane + 128];
        const float a = acts[lvl];
        acc0.x = fmaf(a, bf16_to_f32(h0.x), acc0.x);
        acc0.y = fmaf(a, bf16_to_f32(h0.y), acc0.y);
        acc0.z = fmaf(a, bf16_to_f32(h0.z), acc0.z);
        acc0.w = fmaf(a, bf16_to_f32(h0.w), acc0.w);
        acc1.x = fmaf(a, bf16_to_f32(h1.x), acc1.x);
        acc1.y = fmaf(a, bf16_to_f32(h1.y), acc1.y);
        acc1.z = fmaf(a, bf16_to_f32(h1.z), acc1.z);
        acc1.w = fmaf(a, bf16_to_f32(h1.w), acc1.w);
        acc2.x = fmaf(a, bf16_to_f32(h2.x), acc2.x);
        acc2.y = fmaf(a, bf16_to_f32(h2.y), acc2.y);
        acc2.z = fmaf(a, bf16_to_f32(h2.z), acc2.z);
        acc2.w = fmaf(a, bf16_to_f32(h2.w), acc2.w);
        node = 2 * node + 1 + ((bits >> lvl) & 1);
    }

    float4* __restrict__ of4 = (float4*)out;
    const int ob = b * FFF_ROWF4 + lane;
    of4[ob]       = acc0;
    of4[ob + 64]  = acc1;
    of4[ob + 128] = acc2;
}

// Fallback (ws too small): the proven R11 all-f32 kernel.
__global__ void __launch_bounds__(1024) fff_sparse_kernel_f32(
    const float* __restrict__ x,
    const float* __restrict__ w1s,
    const float* __restrict__ w2s,
    float* __restrict__ out,
    int B)
{
    const int wave = threadIdx.x >> 6;
    const int lane = threadIdx.x & 63;
    const int b = blockIdx.x * WAVES_PER_BLOCK + wave;
    if (b >= B) return;

    const float4* __restrict__ xf4  = (const float4*)x;
    const float4* __restrict__ w1f4 = (const float4*)w1s;
    const float4* __restrict__ w2f4 = (const float4*)w2s;

    const int xb = b * FFF_ROWF4 + lane;
    const float4 xv0 = xf4[xb];
    const float4 xv1 = xf4[xb + 64];
    const float4 xv2 = xf4[xb + 128];

    float acts[FFF_LVLS];
    int bits = 0;
    int node = 0;

#pragma unroll
    for (int lvl = 0; lvl < FFF_LVLS; ++lvl) {
        const int r = node * FFF_ROWF4 + lane;
        const float4 a0 = w1f4[r];
        const float4 a1 = w1f4[r + 64];
        const float4 a2 = w1f4[r + 128];
        float q0 = xv0.x * a0.x;
        float q1 = xv0.y * a0.y;
        q0 = fmaf(xv0.z, a0.z, q0);
        q1 = fmaf(xv0.w, a0.w, q1);
        q0 = fmaf(xv1.x, a1.x, q0);
        q1 = fmaf(xv1.y, a1.y, q1);
        q0 = fmaf(xv1.z, a1.z, q0);
        q1 = fmaf(xv1.w, a1.w, q1);
        q0 = fmaf(xv2.x, a2.x, q0);
        q1 = fmaf(xv2.y, a2.y, q1);
        q0 = fmaf(xv2.z, a2.z, q0);
        q1 = fmaf(xv2.w, a2.w, q1);
        float p = wave_allsum_f32(q0 + q1);
        if (__builtin_expect(fabsf(p) < 1e-4f, 0)) {
            double d0 = (double)xv0.x * (double)a0.x;
            double d1 = (double)xv0.y * (double)a0.y;
            d0 += (double)xv0.z * (double)a0.z;
            d1 += (double)xv0.w * (double)a0.w;
            d0 += (double)xv1.x * (double)a1.x;
            d1 += (double)xv1.y * (double)a1.y;
            d0 += (double)xv1.z * (double)a1.z;
            d1 += (double)xv1.w * (double)a1.w;
            d0 += (double)xv2.x * (double)a2.x;
            d1 += (double)xv2.y * (double)a2.y;
            d0 += (double)xv2.z * (double)a2.z;
            d1 += (double)xv2.w * (double)a2.w;
            double pd = d0 + d1;
#pragma unroll
            for (int m = 32; m > 0; m >>= 1) pd += __shfl_xor(pd, m, 64);
            p = (float)pd;
        }
        acts[lvl] = gelu_exact(p);
        const int s = (p >= 0.0f) ? 1 : 0;
        bits |= s << lvl;
        node = 2 * node + 1 + s;
    }

    float4 acc0 = make_float4(0.f, 0.f, 0.f, 0.f);
    float4 acc1 = make_float4(0.f, 0.f, 0.f, 0.f);
    float4 acc2 = make_float4(0.f, 0.f, 0.f, 0.f);
    node = 0;
#pragma unroll
    for (int lvl = 0; lvl < FFF_LVLS; ++lvl) {
        const int r = node * FFF_ROWF4 + lane;
        const float4 c0 = w2f4[r];
        const float4 c1 = w2f4[r + 64];
        const float4 c2 = w2f4[r + 128];
        const float a = acts[lvl];
        acc0.x = fmaf(a, c0.x, acc0.x); acc0.y = fmaf(a, c0.y, acc0.y);
        acc0.z = fmaf(a, c0.z, acc0.z); acc0.w = fmaf(a, c0.w, acc0.w);
        acc1.x = fmaf(a, c1.x, acc1.x); acc1.y = fmaf(a, c1.y, acc1.y);
        acc1.z = fmaf(a, c1.z, acc1.z); acc1.w = fmaf(a, c1.w, acc1.w);
        acc2.x = fmaf(a, c2.x, acc2.x); acc2.y = fmaf(a, c2.y, acc2.y);
        acc2.z = fmaf(a, c2.z, acc2.z); acc2.w = fmaf(a, c2.w, acc2.w);
        node = 2 * node + 1 + ((bits >> lvl) & 1);
    }

    float4* __restrict__ of4 = (float4*)out;
    const int ob = b * FFF_ROWF4 + lane;
    of4[ob]       = acc0;
    of4[ob + 64]  = acc1;
    of4[ob + 128] = acc2;
}

extern "C" void kernel_launch(void* const* d_in, const int* in_sizes, int n_in,
                              void* d_out, int out_size, void* d_ws, size_t ws_size,
                              hipStream_t stream) {
    const float* x   = (const float*)d_in[0];
    const float* w1s = (const float*)d_in[1];
    const float* w2s = (const float*)d_in[2];
    float* out = (float*)d_out;

    const int B = out_size / FFF_D;                        // 16384
    const int blocks = (B + WAVES_PER_BLOCK - 1) / WAVES_PER_BLOCK;

    const size_t n_elems = (size_t)FFF_NODES * FFF_D;      // 3,144,960
    const size_t needed = 2 * n_elems * sizeof(unsigned short);

    if (ws_size >= needed) {
        unsigned short* w1b = (unsigned short*)d_ws;
        unsigned short* w2b = w1b + n_elems;
        const int nf4 = (int)(n_elems / 4);                // 786,240
        const int cblocks = (2 * nf4 + 1023) / 1024;
        fff_convert_kernel<<<cblocks, 1024, 0, stream>>>(
            (const float4*)w1s, (const float4*)w2s,
            (ushort4*)w1b, (ushort4*)w2b, nf4);
        fff_sparse_kernel_bf16<<<blocks, WAVES_PER_BLOCK * 64, 0, stream>>>(
            x, w1s, (const ushort4*)w1b, (const ushort4*)w2b, out, B);
    } else {
        fff_sparse_kernel_f32<<<blocks, WAVES_PER_BLOCK * 64, 0, stream>>>(
            x, w1s, w2s, out, B);
    }
}